// Round 8
// baseline (130.441 us; speedup 1.0000x reference)
//
#include <hip/hip_runtime.h>
#include <hip/hip_bf16.h>
#include <cstdint>

#define N_PTS 8192
#define DIM 128
// 32-row x 64-col wave tiles over the upper triangle.
// Row-tiles I in [0,256), col-tiles J in [0,128), jmin(I) = I>>1.
// count(I) = 128 - (I>>1); offset(I) = 128*I - floor((I-1)^2/4); total 16512.
#define NBLK 16512

// Base-2-domain circle-loss constants (gamma=256, m=0.25, folded log2(e)).
// lp_nat = (1.25-s)(0.75-s)*256 = 256 s^2 - 512 s + 240   (1.25-s>0 always)
// ln_nat = max(s+0.25,0)*(s-0.25)*256 = (s>-0.25) ? 256 s^2 - 16 : 0
#define KC2 369.3299304675746f    //  256*log2e
#define KC1 -738.6598609351493f   // -512*log2e
#define KC0 346.2468098133512f    //  240*log2e
#define KCN0 -23.083120654223414f // -16*log2e
#define NEGH -1e30f
#define LN2F 0.6931471805599453f

typedef __attribute__((ext_vector_type(8))) __bf16 bf16x8;
typedef __attribute__((ext_vector_type(4))) float f32x4;

// RNE float -> bf16 bits (inputs are finite, no NaN handling needed)
__device__ __forceinline__ unsigned short f2bf(float x) {
  unsigned int u = __float_as_uint(x);
  unsigned int r = (u + 0x7FFFu + ((u >> 16) & 1u)) >> 16;
  return (unsigned short)r;
}

// 32 lanes per row (float4/lane), 8 rows per block: L2-normalize, store bf16.
// Also: pack labels to u8.
__global__ __launch_bounds__(256) void normalize_kernel(const float* __restrict__ feat,
                                                        const int* __restrict__ labels,
                                                        unsigned short* __restrict__ fb,
                                                        unsigned char* __restrict__ lab8) {
  const int gid = blockIdx.x * 256 + threadIdx.x;
  if (gid < N_PTS) lab8[gid] = (unsigned char)labels[gid];
  const int row = blockIdx.x * 8 + (threadIdx.x >> 5);
  const int l32 = threadIdx.x & 31;
  const float4 v = *(const float4*)(feat + row * DIM + l32 * 4);
  float ss = v.x * v.x + v.y * v.y + v.z * v.z + v.w * v.w;
#pragma unroll
  for (int o = 16; o > 0; o >>= 1) ss += __shfl_xor(ss, o);  // stays in 32-group
  const float inv = 1.0f / fmaxf(sqrtf(ss), 1e-12f);
  uint2 pack;
  pack.x = (unsigned int)f2bf(v.x * inv) | ((unsigned int)f2bf(v.y * inv) << 16);
  pack.y = (unsigned int)f2bf(v.z * inv) | ((unsigned int)f2bf(v.w * inv) << 16);
  *(uint2*)(fb + row * DIM + l32 * 4) = pack;
}

// Wave-independent 32x64 tiles, zero LDS, zero barriers, with a 2-deep
// K-loop register pipeline. Round-7 post-mortem: dbuf@2waves/SIMD (r6) hid
// K-latency but exposed the serial epilogue; nodbuf@5waves (r7) overlapped
// epilogues but exposed 4 serial L2 round-trips per wave. This version does
// BOTH: frags 48 + acc 32 + ~30 scalar = ~110 unified regs -> 4 waves/SIMD
// with in-wave K pipelining.
__global__ __launch_bounds__(256) void pair_kernel(const unsigned short* __restrict__ f,
                                                   const unsigned char* __restrict__ lab8,
                                                   float4* __restrict__ partials) {
  const int lane = threadIdx.x & 63;
  const int tid = blockIdx.x * 4 + (threadIdx.x >> 6);  // tile id, 0..NBLK-1

  // decode tid -> (I,J): offset(I) = 128I - floor((I-1)^2/4), exact quadratic
  // guess I = 2*(128.5 - sqrt(16512 - tid)), then +-1 fixup.
#define OFF(I) (128 * (I) - (((I) - 1) * ((I) - 1)) / 4)
  int I = (int)(2.0f * (128.5f - sqrtf(16512.0f - (float)tid)));
  I = I < 0 ? 0 : (I > 255 ? 255 : I);
  while (OFF(I) > tid) --I;
  while (OFF(I + 1) <= tid) ++I;
  const int J = (I >> 1) + (tid - OFF(I));
#undef OFF

  const int rsel = lane & 15, kgrp = lane >> 4;
  const int rowA0 = I * 32, rowB0 = J * 64;

  // per-lane fragment base pointers (16B aligned)
  const unsigned short* pA = f + (size_t)(rowA0 + rsel) * DIM + kgrp * 8;
  const unsigned short* pB = f + (size_t)(rowB0 + rsel) * DIM + kgrp * 8;

  // epilogue label gathers issued early; latency hides under the K-loop.
  // lj packed 4x u8 into one reg (register trim).
  const int ibase = rowA0 + kgrp * 4;
  const int jbase = rowB0 + rsel;
  unsigned int liPack[2];
  unsigned int ljPack = 0;
#pragma unroll
  for (int tn = 0; tn < 4; ++tn)
    ljPack |= ((unsigned int)lab8[jbase + tn * 16]) << (tn * 8);
#pragma unroll
  for (int tm = 0; tm < 2; ++tm)
    liPack[tm] = *(const unsigned int*)(lab8 + ibase + tm * 16);  // 4 labels packed

  f32x4 acc[2][4];
#pragma unroll
  for (int a = 0; a < 2; ++a)
#pragma unroll
    for (int b = 0; b < 4; ++b) acc[a][b] = (f32x4){0.f, 0.f, 0.f, 0.f};

#define LOADF(FA, FB, KK)                                            \
  do {                                                               \
    _Pragma("unroll") for (int x = 0; x < 2; ++x)                    \
        FA[x] = *(const bf16x8*)(pA + x * 16 * DIM + (KK) * 32);     \
    _Pragma("unroll") for (int x = 0; x < 4; ++x)                    \
        FB[x] = *(const bf16x8*)(pB + x * 16 * DIM + (KK) * 32);     \
  } while (0)
#define MFMA8(FA, FB)                                                \
  do {                                                               \
    _Pragma("unroll") for (int tm = 0; tm < 2; ++tm)                 \
        _Pragma("unroll") for (int tn = 0; tn < 4; ++tn)             \
            acc[tm][tn] = __builtin_amdgcn_mfma_f32_16x16x32_bf16(   \
                FA[tm], FB[tn], acc[tm][tn], 0, 0, 0);               \
  } while (0)

  {
    bf16x8 a0[2], b0[4], a1[2], b1[4];
    LOADF(a0, b0, 0);
    LOADF(a1, b1, 1);   // 2 K-steps in flight
    MFMA8(a0, b0);
    LOADF(a0, b0, 2);   // issued behind step-0 MFMAs, used 2 steps later
    MFMA8(a1, b1);
    LOADF(a1, b1, 3);
    MFMA8(a0, b0);
    MFMA8(a1, b1);
  }
#undef LOADF
#undef MFMA8

  // ---- epilogue: circle-loss logits (base-2 domain) + in-wave logsumexp ----
  // C/D mapping (16x16x32): col = lane&15 (j/B side), row = (lane>>4)*4 + reg
  // Selected-constant form: u = fma(s, s*KC2 + (eq?KC1:0), eq?KC0:KCN0),
  // then the negative-stream clamp (!eq && s<=-0.25 -> logit 0).

  // pass 1: selected logit in-place, per-thread maxes
  float mp = NEGH, mn = NEGH;
  if (2 * J > I) {  // tile fully above the diagonal: all pairs valid (j > i)
#pragma unroll
    for (int tm = 0; tm < 2; ++tm)
#pragma unroll
      for (int tn = 0; tn < 4; ++tn) {
        const unsigned int ljB = (ljPack >> (tn * 8)) & 0xFFu;
#pragma unroll
        for (int r = 0; r < 4; ++r) {
          const float s = acc[tm][tn][r];
          const bool eq = (((liPack[tm] >> (r * 8)) & 0xFFu) == ljB);
          float u = fmaf(s, fmaf(s, KC2, eq ? KC1 : 0.f), eq ? KC0 : KCN0);
          u = (!eq && s <= -0.25f) ? 0.f : u;
          acc[tm][tn][r] = u;
          mp = fmaxf(mp, eq ? u : NEGH);
          mn = fmaxf(mn, eq ? NEGH : u);
        }
      }
  } else {  // diagonal-straddling tile: mask out j <= i
#pragma unroll
    for (int tm = 0; tm < 2; ++tm)
#pragma unroll
      for (int tn = 0; tn < 4; ++tn) {
        const unsigned int ljB = (ljPack >> (tn * 8)) & 0xFFu;
        const int d = (jbase + tn * 16) - (ibase + tm * 16);  // valid iff d > r
#pragma unroll
        for (int r = 0; r < 4; ++r) {
          const float s = acc[tm][tn][r];
          const bool eq = (((liPack[tm] >> (r * 8)) & 0xFFu) == ljB);
          float u = fmaf(s, fmaf(s, KC2, eq ? KC1 : 0.f), eq ? KC0 : KCN0);
          u = (!eq && s <= -0.25f) ? 0.f : u;
          const bool valid = d > r;
          u = valid ? u : NEGH;
          acc[tm][tn][r] = u;
          mp = fmaxf(mp, (eq && valid) ? u : NEGH);
          mn = fmaxf(mn, (!eq && valid) ? u : NEGH);
        }
      }
  }
  // in-wave butterfly: all 64 lanes end with the wave max (no LDS, no barrier)
#pragma unroll
  for (int o = 32; o > 0; o >>= 1) {
    mp = fmaxf(mp, __shfl_xor(mp, o));
    mn = fmaxf(mn, __shfl_xor(mn, o));
  }
  // Clamp keeps exp2(NEGH - M) == 0 even when a stream is empty in this tile.
  const float Mp = fmaxf(mp, -1e28f);
  const float Mn = fmaxf(mn, -1e28f);

  // pass 2: one exp2 per element, route to the owning stream
  float sp = 0.f, sn = 0.f;
#pragma unroll
  for (int tm = 0; tm < 2; ++tm)
#pragma unroll
    for (int tn = 0; tn < 4; ++tn) {
      const unsigned int ljB = (ljPack >> (tn * 8)) & 0xFFu;
#pragma unroll
      for (int r = 0; r < 4; ++r) {
        const bool eq = (((liPack[tm] >> (r * 8)) & 0xFFu) == ljB);
        const float e = __builtin_amdgcn_exp2f(acc[tm][tn][r] - (eq ? Mp : Mn));
        sp += eq ? e : 0.f;
        sn += eq ? 0.f : e;
      }
    }
#pragma unroll
  for (int o = 32; o > 0; o >>= 1) {
    sp += __shfl_xor(sp, o);
    sn += __shfl_xor(sn, o);
  }
  if (lane == 0) partials[tid] = make_float4(Mp, sp, Mn, sn);
}

// Merge 16512 (m2,s2) base-2 partials for both streams; softplus(lse_p+lse_n).
__global__ __launch_bounds__(256) void finalize_kernel(const float4* __restrict__ partials,
                                                       float* __restrict__ out) {
  const int t = threadIdx.x;
  float mp = NEGH, sp = 0.f, mn = NEGH, sn = 0.f;
  for (int i = t; i < NBLK; i += 256) {
    const float4 p = partials[i];
    {
      const float m = fmaxf(mp, p.x);
      sp = sp * __builtin_amdgcn_exp2f(mp - m) + p.y * __builtin_amdgcn_exp2f(p.x - m);
      mp = m;
    }
    {
      const float m = fmaxf(mn, p.z);
      sn = sn * __builtin_amdgcn_exp2f(mn - m) + p.w * __builtin_amdgcn_exp2f(p.z - m);
      mn = m;
    }
  }
  __shared__ float smp[256], ssp[256], smn[256], ssn[256];
  smp[t] = mp; ssp[t] = sp; smn[t] = mn; ssn[t] = sn;
  __syncthreads();
  for (int off = 128; off > 0; off >>= 1) {
    if (t < off) {
      {
        const float m2 = smp[t + off], s2 = ssp[t + off];
        const float m = fmaxf(smp[t], m2);
        ssp[t] = ssp[t] * __builtin_amdgcn_exp2f(smp[t] - m) + s2 * __builtin_amdgcn_exp2f(m2 - m);
        smp[t] = m;
      }
      {
        const float m2 = smn[t + off], s2 = ssn[t + off];
        const float m = fmaxf(smn[t], m2);
        ssn[t] = ssn[t] * __builtin_amdgcn_exp2f(smn[t] - m) + s2 * __builtin_amdgcn_exp2f(m2 - m);
        smn[t] = m;
      }
    }
    __syncthreads();
  }
  if (t == 0) {
    const float lsep = (smp[0] + __builtin_amdgcn_logf(ssp[0])) * LN2F;  // base-2 -> nat
    const float lsen = (smn[0] + __builtin_amdgcn_logf(ssn[0])) * LN2F;
    const float x = lsep + lsen;
    out[0] = fmaxf(x, 0.f) + log1pf(__expf(-fabsf(x)));  // stable softplus
  }
}

extern "C" void kernel_launch(void* const* d_in, const int* in_sizes, int n_in,
                              void* d_out, int out_size, void* d_ws, size_t ws_size,
                              hipStream_t stream) {
  const float* feat = (const float*)d_in[0];
  const int* labels = (const int*)d_in[1];
  float* out = (float*)d_out;

  unsigned short* fb = (unsigned short*)d_ws;                    // 2 MiB
  char* base = (char*)d_ws + (size_t)N_PTS * DIM * 2;
  float4* partials = (float4*)base;                              // 16512*16 = 258 KiB
  unsigned char* lab8 = (unsigned char*)(base + (size_t)NBLK * 16);  // 8192 B

  normalize_kernel<<<N_PTS / 8, 256, 0, stream>>>(feat, labels, fb, lab8);
  pair_kernel<<<NBLK / 4, 256, 0, stream>>>(fb, lab8, partials);
  finalize_kernel<<<1, 256, 0, stream>>>(partials, out);
}

// Round 9
// 120.055 us; speedup vs baseline: 1.0865x; 1.0865x over previous
//
#include <hip/hip_runtime.h>
#include <hip/hip_bf16.h>
#include <cstdint>

#define N_PTS 8192
#define DIM 128
// 32-row x 64-col wave tiles over the upper triangle.
// Row-tiles I in [0,256), col-tiles J in [0,128), jmin(I) = I>>1.
// count(I) = 128 - (I>>1); offset(I) = 128*I - floor((I-1)^2/4); total 16512.
// Each WAVE processes TWO consecutive tiles (tid0=2*wid, tid1=tid0+1),
// pipelining T1's K-loop under T0's epilogue.
#define NBLK 16512

// Base-2-domain circle-loss constants (gamma=256, m=0.25, folded log2(e)).
#define KC2 369.3299304675746f    //  256*log2e
#define KC1 -738.6598609351493f   // -512*log2e
#define KC0 346.2468098133512f    //  240*log2e
#define KCN0 -23.083120654223414f // -16*log2e
#define NEGH -1e30f
#define LN2F 0.6931471805599453f

typedef __attribute__((ext_vector_type(8))) __bf16 bf16x8;
typedef __attribute__((ext_vector_type(4))) float f32x4;

// RNE float -> bf16 bits (inputs are finite, no NaN handling needed)
__device__ __forceinline__ unsigned short f2bf(float x) {
  unsigned int u = __float_as_uint(x);
  unsigned int r = (u + 0x7FFFu + ((u >> 16) & 1u)) >> 16;
  return (unsigned short)r;
}

// 32 lanes per row (float4/lane), 8 rows per block: L2-normalize, store bf16.
// Also: pack labels to u8.
__global__ __launch_bounds__(256) void normalize_kernel(const float* __restrict__ feat,
                                                        const int* __restrict__ labels,
                                                        unsigned short* __restrict__ fb,
                                                        unsigned char* __restrict__ lab8) {
  const int gid = blockIdx.x * 256 + threadIdx.x;
  if (gid < N_PTS) lab8[gid] = (unsigned char)labels[gid];
  const int row = blockIdx.x * 8 + (threadIdx.x >> 5);
  const int l32 = threadIdx.x & 31;
  const float4 v = *(const float4*)(feat + row * DIM + l32 * 4);
  float ss = v.x * v.x + v.y * v.y + v.z * v.z + v.w * v.w;
#pragma unroll
  for (int o = 16; o > 0; o >>= 1) ss += __shfl_xor(ss, o);  // stays in 32-group
  const float inv = 1.0f / fmaxf(sqrtf(ss), 1e-12f);
  uint2 pack;
  pack.x = (unsigned int)f2bf(v.x * inv) | ((unsigned int)f2bf(v.y * inv) << 16);
  pack.y = (unsigned int)f2bf(v.z * inv) | ((unsigned int)f2bf(v.w * inv) << 16);
  *(uint2*)(fb + row * DIM + l32 * 4) = pack;
}

// ---- shared macros for the pair kernel ----
#define OFFI(I) (128 * (I) - (((I) - 1) * ((I) - 1)) / 4)
#define DECODE(TID, IV, JV)                                              \
  do {                                                                   \
    int _i = (int)(2.0f * (128.5f - sqrtf(16512.0f - (float)(TID))));    \
    _i = _i < 0 ? 0 : (_i > 255 ? 255 : _i);                             \
    while (OFFI(_i) > (TID)) --_i;                                       \
    while (OFFI(_i + 1) <= (TID)) ++_i;                                  \
    IV = _i;                                                             \
    JV = (_i >> 1) + ((TID)-OFFI(_i));                                   \
  } while (0)

#define LOADF(PA, PB, FA, FB, KK)                                        \
  do {                                                                   \
    _Pragma("unroll") for (int x = 0; x < 2; ++x)                        \
        FA[x] = *(const bf16x8*)((PA) + x * 16 * DIM + (KK)*32);         \
    _Pragma("unroll") for (int x = 0; x < 4; ++x)                        \
        FB[x] = *(const bf16x8*)((PB) + x * 16 * DIM + (KK)*32);         \
  } while (0)

#define MFMA8(ACC, FA, FB)                                               \
  do {                                                                   \
    _Pragma("unroll") for (int tm = 0; tm < 2; ++tm)                     \
        _Pragma("unroll") for (int tn = 0; tn < 4; ++tn)                 \
            ACC[tm][tn] = __builtin_amdgcn_mfma_f32_16x16x32_bf16(       \
                FA[tm], FB[tn], ACC[tm][tn], 0, 0, 0);                   \
  } while (0)

// pass 1: selected logit written in-place, per-thread maxes.
#define PASS1(ACC, LIP, LJP, IB, JB, IV, JV, MP, MN)                              \
  do {                                                                            \
    if (2 * (JV) > (IV)) {                                                        \
      _Pragma("unroll") for (int tm = 0; tm < 2; ++tm)                            \
          _Pragma("unroll") for (int tn = 0; tn < 4; ++tn) {                      \
        const unsigned int ljB = ((LJP) >> (tn * 8)) & 0xFFu;                     \
        _Pragma("unroll") for (int r = 0; r < 4; ++r) {                           \
          const float s = ACC[tm][tn][r];                                         \
          const bool eq = ((((LIP)[tm] >> (r * 8)) & 0xFFu) == ljB);              \
          float u = fmaf(s, fmaf(s, KC2, eq ? KC1 : 0.f), eq ? KC0 : KCN0);       \
          u = (!eq && s <= -0.25f) ? 0.f : u;                                     \
          ACC[tm][tn][r] = u;                                                     \
          MP = fmaxf(MP, eq ? u : NEGH);                                          \
          MN = fmaxf(MN, eq ? NEGH : u);                                          \
        }                                                                         \
      }                                                                           \
    } else {                                                                      \
      _Pragma("unroll") for (int tm = 0; tm < 2; ++tm)                            \
          _Pragma("unroll") for (int tn = 0; tn < 4; ++tn) {                      \
        const unsigned int ljB = ((LJP) >> (tn * 8)) & 0xFFu;                     \
        const int d = ((JB) + tn * 16) - ((IB) + tm * 16); /* valid iff d > r */  \
        _Pragma("unroll") for (int r = 0; r < 4; ++r) {                           \
          const float s = ACC[tm][tn][r];                                         \
          const bool eq = ((((LIP)[tm] >> (r * 8)) & 0xFFu) == ljB);              \
          float u = fmaf(s, fmaf(s, KC2, eq ? KC1 : 0.f), eq ? KC0 : KCN0);       \
          u = (!eq && s <= -0.25f) ? 0.f : u;                                     \
          const bool valid = d > r;                                               \
          u = valid ? u : NEGH;                                                   \
          ACC[tm][tn][r] = u;                                                     \
          MP = fmaxf(MP, (eq && valid) ? u : NEGH);                               \
          MN = fmaxf(MN, (!eq && valid) ? u : NEGH);                              \
        }                                                                         \
      }                                                                           \
    }                                                                             \
  } while (0)

#define BFLY_MAX(MP, MN)                                                 \
  do {                                                                   \
    _Pragma("unroll") for (int o = 32; o > 0; o >>= 1) {                 \
      MP = fmaxf(MP, __shfl_xor(MP, o));                                 \
      MN = fmaxf(MN, __shfl_xor(MN, o));                                 \
    }                                                                    \
    MP = fmaxf(MP, -1e28f); /* keeps exp2(NEGH-M)==0 on empty stream */  \
    MN = fmaxf(MN, -1e28f);                                              \
  } while (0)

// pass 2: one exp2 per element, route to owning stream.
#define PASS2(ACC, LIP, LJP, MPV, MNV, SP, SN)                           \
  do {                                                                   \
    _Pragma("unroll") for (int tm = 0; tm < 2; ++tm)                     \
        _Pragma("unroll") for (int tn = 0; tn < 4; ++tn) {               \
      const unsigned int ljB = ((LJP) >> (tn * 8)) & 0xFFu;              \
      _Pragma("unroll") for (int r = 0; r < 4; ++r) {                    \
        const bool eq = ((((LIP)[tm] >> (r * 8)) & 0xFFu) == ljB);       \
        const float e =                                                  \
            __builtin_amdgcn_exp2f(ACC[tm][tn][r] - (eq ? MPV : MNV));   \
        SP += eq ? e : 0.f;                                              \
        SN += eq ? 0.f : e;                                              \
      }                                                                  \
    }                                                                    \
  } while (0)

#define BFLY_SUM(SP, SN)                                                 \
  do {                                                                   \
    _Pragma("unroll") for (int o = 32; o > 0; o >>= 1) {                 \
      SP += __shfl_xor(SP, o);                                           \
      SN += __shfl_xor(SN, o);                                           \
    }                                                                    \
  } while (0)

// Wave-independent 32x64 tiles, zero LDS, zero barriers; TWO tiles per wave
// with cross-tile pipelining: T1's fragment loads + MFMAs are interleaved
// with T0's epilogue phases, so the VALU-heavy epilogue hides T1's L2
// latency and T1's MFMAs run in the matrix pipe under epilogue VALU.
// Round-8 post-mortem: occupancy (2->5 waves/SIMD) did NOT move the 51-56us
// plateau; the stall is within-wave phase serialization, attacked here.
__global__ __launch_bounds__(256) void pair_kernel(const unsigned short* __restrict__ f,
                                                   const unsigned char* __restrict__ lab8,
                                                   float4* __restrict__ partials) {
  const int lane = threadIdx.x & 63;
  const int wid = blockIdx.x * 4 + (threadIdx.x >> 6);
  const int tid0 = wid * 2, tid1 = tid0 + 1;

  int I0, J0, I1, J1;
  DECODE(tid0, I0, J0);
  DECODE(tid1, I1, J1);

  const int rsel = lane & 15, kgrp = lane >> 4;
  const unsigned short* pA0 = f + (size_t)(I0 * 32 + rsel) * DIM + kgrp * 8;
  const unsigned short* pB0 = f + (size_t)(J0 * 64 + rsel) * DIM + kgrp * 8;
  const unsigned short* pA1 = f + (size_t)(I1 * 32 + rsel) * DIM + kgrp * 8;
  const unsigned short* pB1 = f + (size_t)(J1 * 64 + rsel) * DIM + kgrp * 8;

  // label gathers for both tiles, issued early (latency under T0's K-loop)
  const int ibase0 = I0 * 32 + kgrp * 4, jbase0 = J0 * 64 + rsel;
  const int ibase1 = I1 * 32 + kgrp * 4, jbase1 = J1 * 64 + rsel;
  unsigned int liP0[2], liP1[2], ljP0 = 0, ljP1 = 0;
#pragma unroll
  for (int tn = 0; tn < 4; ++tn) {
    ljP0 |= ((unsigned int)lab8[jbase0 + tn * 16]) << (tn * 8);
    ljP1 |= ((unsigned int)lab8[jbase1 + tn * 16]) << (tn * 8);
  }
#pragma unroll
  for (int tm = 0; tm < 2; ++tm) {
    liP0[tm] = *(const unsigned int*)(lab8 + ibase0 + tm * 16);
    liP1[tm] = *(const unsigned int*)(lab8 + ibase1 + tm * 16);
  }

  // ---- T0 K-loop (2-deep frag double-buffer; acc1 not yet live) ----
  f32x4 acc0[2][4];
#pragma unroll
  for (int a = 0; a < 2; ++a)
#pragma unroll
    for (int b = 0; b < 4; ++b) acc0[a][b] = (f32x4){0.f, 0.f, 0.f, 0.f};
  {
    bf16x8 xa[2], xb[4], ya[2], yb[4];
    LOADF(pA0, pB0, xa, xb, 0);
    LOADF(pA0, pB0, ya, yb, 1);
    MFMA8(acc0, xa, xb);
    LOADF(pA0, pB0, xa, xb, 2);
    MFMA8(acc0, ya, yb);
    LOADF(pA0, pB0, ya, yb, 3);
    MFMA8(acc0, xa, xb);
    MFMA8(acc0, ya, yb);
  }

  // ---- T1 K-loop interleaved with T0 epilogue ----
  f32x4 acc1[2][4];
#pragma unroll
  for (int a = 0; a < 2; ++a)
#pragma unroll
    for (int b = 0; b < 4; ++b) acc1[a][b] = (f32x4){0.f, 0.f, 0.f, 0.f};

  bf16x8 ca[2], cb[4];
  LOADF(pA1, pB1, ca, cb, 0);         // batch 0 in flight...
  float mp0 = NEGH, mn0 = NEGH;
  PASS1(acc0, liP0, ljP0, ibase0, jbase0, I0, J0, mp0, mn0);  // ...hidden here
  MFMA8(acc1, ca, cb);
  LOADF(pA1, pB1, ca, cb, 1);         // batch 1 in flight...
  BFLY_MAX(mp0, mn0);                 // ...hidden under shuffle chain
  float sp0 = 0.f, sn0 = 0.f;
  PASS2(acc0, liP0, ljP0, mp0, mn0, sp0, sn0);
  MFMA8(acc1, ca, cb);
  LOADF(pA1, pB1, ca, cb, 2);         // batch 2 in flight...
  BFLY_SUM(sp0, sn0);                 // ...hidden under sum chain
  if (lane == 0) partials[tid0] = make_float4(mp0, sp0, mn0, sn0);
  MFMA8(acc1, ca, cb);
  LOADF(pA1, pB1, ca, cb, 3);
  MFMA8(acc1, ca, cb);

  // ---- T1 epilogue ----
  float mp1 = NEGH, mn1 = NEGH;
  PASS1(acc1, liP1, ljP1, ibase1, jbase1, I1, J1, mp1, mn1);
  BFLY_MAX(mp1, mn1);
  float sp1 = 0.f, sn1 = 0.f;
  PASS2(acc1, liP1, ljP1, mp1, mn1, sp1, sn1);
  BFLY_SUM(sp1, sn1);
  if (lane == 0) partials[tid1] = make_float4(mp1, sp1, mn1, sn1);
}

// Merge 16512 (m2,s2) base-2 partials for both streams; softplus(lse_p+lse_n).
// 1024 threads: 16 strided rounds instead of 64 (fewer serial L2 latencies).
__global__ __launch_bounds__(1024) void finalize_kernel(const float4* __restrict__ partials,
                                                        float* __restrict__ out) {
  const int t = threadIdx.x;
  float mp = NEGH, sp = 0.f, mn = NEGH, sn = 0.f;
  for (int i = t; i < NBLK; i += 1024) {
    const float4 p = partials[i];
    {
      const float m = fmaxf(mp, p.x);
      sp = sp * __builtin_amdgcn_exp2f(mp - m) + p.y * __builtin_amdgcn_exp2f(p.x - m);
      mp = m;
    }
    {
      const float m = fmaxf(mn, p.z);
      sn = sn * __builtin_amdgcn_exp2f(mn - m) + p.w * __builtin_amdgcn_exp2f(p.z - m);
      mn = m;
    }
  }
  __shared__ float smp[1024], ssp[1024], smn[1024], ssn[1024];
  smp[t] = mp; ssp[t] = sp; smn[t] = mn; ssn[t] = sn;
  __syncthreads();
  for (int off = 512; off > 0; off >>= 1) {
    if (t < off) {
      {
        const float m2 = smp[t + off], s2 = ssp[t + off];
        const float m = fmaxf(smp[t], m2);
        ssp[t] = ssp[t] * __builtin_amdgcn_exp2f(smp[t] - m) + s2 * __builtin_amdgcn_exp2f(m2 - m);
        smp[t] = m;
      }
      {
        const float m2 = smn[t + off], s2 = ssn[t + off];
        const float m = fmaxf(smn[t], m2);
        ssn[t] = ssn[t] * __builtin_amdgcn_exp2f(smn[t] - m) + s2 * __builtin_amdgcn_exp2f(m2 - m);
        smn[t] = m;
      }
    }
    __syncthreads();
  }
  if (t == 0) {
    const float lsep = (smp[0] + __builtin_amdgcn_logf(ssp[0])) * LN2F;  // base-2 -> nat
    const float lsen = (smn[0] + __builtin_amdgcn_logf(ssn[0])) * LN2F;
    const float x = lsep + lsen;
    out[0] = fmaxf(x, 0.f) + log1pf(__expf(-fabsf(x)));  // stable softplus
  }
}

extern "C" void kernel_launch(void* const* d_in, const int* in_sizes, int n_in,
                              void* d_out, int out_size, void* d_ws, size_t ws_size,
                              hipStream_t stream) {
  const float* feat = (const float*)d_in[0];
  const int* labels = (const int*)d_in[1];
  float* out = (float*)d_out;

  unsigned short* fb = (unsigned short*)d_ws;                        // 2 MiB
  char* base = (char*)d_ws + (size_t)N_PTS * DIM * 2;
  float4* partials = (float4*)base;                                  // 16512*16 = 258 KiB
  unsigned char* lab8 = (unsigned char*)(base + (size_t)NBLK * 16);  // 8192 B

  normalize_kernel<<<N_PTS / 8, 256, 0, stream>>>(feat, labels, fb, lab8);
  pair_kernel<<<NBLK / 8, 256, 0, stream>>>(fb, lab8, partials);  // 2064 blocks
  finalize_kernel<<<1, 1024, 0, stream>>>(partials, out);
}